// Round 6
// baseline (659.551 us; speedup 1.0000x reference)
//
#include <hip/hip_runtime.h>
#include <stdint.h>

typedef unsigned short u16;
typedef unsigned int u32;

#define T_TOK 8192      // B*S tokens
#define DIMSZ 1024
#define HIDSZ 1024
#define NE 8
#define NSLOT (T_TOK * 2)

typedef __attribute__((ext_vector_type(8))) __bf16 bf16x8;
typedef __attribute__((ext_vector_type(4))) float f32x4;

// LDS layout [kc][row][8] (u16), unpadded. Staging: lane<->row, wave<->kc so
// each wave's ds_write_b128 stream is base + lane*16B (contiguous 1KB) -- the
// pattern measured at 0 conflicts in r3 (DMA-written same layout). Fragment
// reads (fixed kc per 16-lane group, rows lm=0..15) = r3-measured 0 conflicts.

__device__ __forceinline__ u16 f2bf(float f) {
  u32 u = __builtin_bit_cast(u32, f);
  u += 0x7FFFu + ((u >> 16) & 1u);   // RNE
  return (u16)(u >> 16);
}
__device__ __forceinline__ float bflo(u32 v) { return __builtin_bit_cast(float, v << 16); }
__device__ __forceinline__ float bfhi(u32 v) { return __builtin_bit_cast(float, v & 0xffff0000u); }
__device__ __forceinline__ u32 pack2(float a, float b) {
  return (u32)f2bf(a) | ((u32)f2bf(b) << 16);
}
__device__ __forceinline__ float silu_f(float v) { return v / (1.f + expf(-v)); }

// ---------------- fp32 -> bf16 weight conversion (3 tensors per launch) ------
__global__ __launch_bounds__(256) void convert3_kernel(
    const float* __restrict__ s0, const float* __restrict__ s1,
    const float* __restrict__ s2, u16* __restrict__ d0, u16* __restrict__ d1,
    u16* __restrict__ d2, int n4) {
  const float* s = (blockIdx.y == 0) ? s0 : (blockIdx.y == 1) ? s1 : s2;
  u16* d = (blockIdx.y == 0) ? d0 : (blockIdx.y == 1) ? d1 : d2;
  int stride = gridDim.x * 256;
  for (int i = blockIdx.x * 256 + threadIdx.x; i < n4; i += stride) {
    float4 v = ((const float4*)s)[i];
    uint2 p;
    p.x = pack2(v.x, v.y);
    p.y = pack2(v.z, v.w);
    ((uint2*)d)[i] = p;
  }
}

// ---------------- router: fp32 scores, top-2; emits bf16(x); NO atomics ------
__global__ __launch_bounds__(256) void router_kernel(
    const float* __restrict__ x, const float* __restrict__ gw,
    const float* __restrict__ bias, int* __restrict__ sel,
    float* __restrict__ selscore, u16* __restrict__ xb) {
  int t = blockIdx.x * 4 + (threadIdx.x >> 6);
  int lane = threadIdx.x & 63;
  float a[NE];
#pragma unroll
  for (int e = 0; e < NE; e++) a[e] = 0.f;
#pragma unroll
  for (int j = 0; j < 4; j++) {
    int c = j * 256 + lane * 4;
    float4 xv = *(const float4*)&x[(size_t)t * DIMSZ + c];
    uint2 p;
    p.x = pack2(xv.x, xv.y);
    p.y = pack2(xv.z, xv.w);
    *(uint2*)&xb[(size_t)t * DIMSZ + c] = p;
#pragma unroll
    for (int e = 0; e < NE; e++) {
      float4 gv = *(const float4*)&gw[e * DIMSZ + c];
      a[e] = fmaf(xv.x, gv.x, fmaf(xv.y, gv.y, fmaf(xv.z, gv.z, fmaf(xv.w, gv.w, a[e]))));
    }
  }
#pragma unroll
  for (int off = 1; off < 64; off <<= 1)
#pragma unroll
    for (int e = 0; e < NE; e++) a[e] += __shfl_xor(a[e], off);
  if (lane == 0) {
    float s[NE], b[NE];
#pragma unroll
    for (int e = 0; e < NE; e++) {
      s[e] = 1.f / (1.f + expf(-a[e]));
      b[e] = s[e] + bias[e];
    }
    int e1 = 0; float v1 = b[0];
#pragma unroll
    for (int e = 1; e < NE; e++) if (b[e] > v1) { v1 = b[e]; e1 = e; }
    int e2 = -1; float v2 = -1e30f;
#pragma unroll
    for (int e = 0; e < NE; e++) if (e != e1 && b[e] > v2) { v2 = b[e]; e2 = e; }
    sel[t * 2] = e1; sel[t * 2 + 1] = e2;
    selscore[t * 2] = s[e1];       // ROUTE_SCALE == 1
    selscore[t * 2 + 1] = s[e2];
  }
}

// ---------------- rank: single block, atomic-free dispatch permutation -------
__global__ __launch_bounds__(1024) void rank_kernel(
    const int* __restrict__ sel, const float* __restrict__ selscore,
    int* __restrict__ slot2pos, float* __restrict__ slot_score,
    int* __restrict__ counts, int* __restrict__ offsets) {
  __shared__ int hist[NE * 1024];
  __shared__ int tot[NE];
  __shared__ int offs[NE];
  int tid = threadIdx.x;
  int sl[16];
  int h[NE];
#pragma unroll
  for (int e = 0; e < NE; e++) h[e] = 0;
#pragma unroll
  for (int j = 0; j < 4; j++) {
    int4 v = ((const int4*)sel)[tid * 4 + j];
    sl[j * 4 + 0] = v.x; sl[j * 4 + 1] = v.y;
    sl[j * 4 + 2] = v.z; sl[j * 4 + 3] = v.w;
  }
#pragma unroll
  for (int i = 0; i < 16; i++)
#pragma unroll
    for (int e = 0; e < NE; e++) h[e] += (sl[i] == e) ? 1 : 0;
#pragma unroll
  for (int e = 0; e < NE; e++) hist[e * 1024 + tid] = h[e];
  __syncthreads();
  int wid = tid >> 6, lane = tid & 63;
  if (wid < NE) {
    int e = wid;
    int vals[16];
    int lsum = 0;
#pragma unroll
    for (int i = 0; i < 16; i++) {
      int v = hist[e * 1024 + lane * 16 + i];
      vals[i] = lsum;
      lsum += v;
    }
    int incl = lsum;
#pragma unroll
    for (int off = 1; off < 64; off <<= 1) {
      int v = __shfl_up(incl, off);
      if (lane >= off) incl += v;
    }
    int excl = incl - lsum;
#pragma unroll
    for (int i = 0; i < 16; i++) hist[e * 1024 + lane * 16 + i] = vals[i] + excl;
    if (lane == 63) tot[e] = incl;
  }
  __syncthreads();
  if (tid == 0) {
    int acc = 0;
    for (int e = 0; e < NE; e++) {
      offs[e] = acc;
      offsets[e] = acc;
      counts[e] = tot[e];
      acc += tot[e];
    }
  }
  __syncthreads();
  int base[NE];
#pragma unroll
  for (int e = 0; e < NE; e++) base[e] = offs[e] + hist[e * 1024 + tid];
#pragma unroll
  for (int i = 0; i < 16; i++) {
    int slot = tid * 16 + i;
    int e = sl[i];
    int pos = 0;
#pragma unroll
    for (int k = 0; k < NE; k++) pos += (e == k) ? base[k] : 0;
#pragma unroll
    for (int k = 0; k < NE; k++) base[k] += (e == k) ? 1 : 0;
    slot2pos[slot] = pos;
    slot_score[pos] = selscore[slot];
  }
}

// ---------------- gather: pure copy, slot -> row pos of bf16(s*x) ------------
__global__ __launch_bounds__(256) void gather_kernel(
    const float* __restrict__ x, const float* __restrict__ selscore,
    const int* __restrict__ slot2pos, u16* __restrict__ routed) {
  int s = blockIdx.x * 4 + (threadIdx.x >> 6);
  int lane = threadIdx.x & 63;
  int pos = slot2pos[s];
  float sc = selscore[s];
  int t = s >> 1;
#pragma unroll
  for (int j = 0; j < 4; j++) {
    int c = j * 256 + lane * 4;
    float4 v = *(const float4*)&x[(size_t)t * DIMSZ + c];
    uint2 p;
    p.x = pack2(v.x * sc, v.y * sc);
    p.y = pack2(v.z * sc, v.w * sc);
    *(uint2*)&routed[(size_t)pos * DIMSZ + c] = p;
  }
}

// ---------------- dual GEMM (G1,G3 share A-tile) + silu*mul -> H bf16 --------
// BM=128 BN=64 BK=32, 256 thr = 4 waves. Staging: lane<->row, wave<->kc,
// LDS [kc][row][8]. z<NE: routed segment z; z==NE: shared expert.
__global__ __launch_bounds__(256) void dual_glu_gemm(
    const u16* __restrict__ A, const u16* __restrict__ W1,
    const u16* __restrict__ W3, u16* __restrict__ Hout,
    const u16* __restrict__ As, const u16* __restrict__ SW1,
    const u16* __restrict__ SW3, u16* __restrict__ Hs,
    const int* __restrict__ seg_off, const int* __restrict__ seg_cnt) {
  int z = blockIdx.z;
  const u16 *Ap, *w1p, *w3p;
  u16* Hp;
  int soff, scnt;
  if (z < NE) {
    soff = seg_off[z]; scnt = seg_cnt[z];
    Ap = A; w1p = W1 + (size_t)z * HIDSZ * DIMSZ; w3p = W3 + (size_t)z * HIDSZ * DIMSZ;
    Hp = Hout;
  } else {
    soff = 0; scnt = T_TOK;
    Ap = As; w1p = SW1; w3p = SW3;
    Hp = Hs;
  }
  int mbase = blockIdx.y * 128;
  if (mbase >= scnt) return;
  int nbase = blockIdx.x * 64;

  __shared__ u16 lA[4 * 128 * 8];
  __shared__ u16 lB1[4 * 64 * 8];
  __shared__ u16 lB3[4 * 64 * 8];

  int tid = threadIdx.x;
  int lane = tid & 63;
  int kc = tid >> 6;                 // wave id == staged k-chunk
  int wy = kc >> 1, wx = kc & 1;     // wave's output quadrant
  int q = lane >> 4, lm = lane & 15;

  f32x4 acc1[4][2], acc3[4][2];
#pragma unroll
  for (int i = 0; i < 4; i++)
#pragma unroll
    for (int j = 0; j < 2; j++) { acc1[i][j] = (f32x4)0.f; acc3[i][j] = (f32x4)0.f; }

  // staging: this thread loads row=lane(+64) of k-chunk kc
  int rg0 = min(mbase + lane, scnt - 1);
  int rg1 = min(mbase + 64 + lane, scnt - 1);
  const u16* gA0 = Ap + (size_t)(soff + rg0) * DIMSZ + kc * 8;
  const u16* gA1 = Ap + (size_t)(soff + rg1) * DIMSZ + kc * 8;
  const u16* gB1 = w1p + (size_t)(nbase + lane) * DIMSZ + kc * 8;
  const u16* gB3 = w3p + (size_t)(nbase + lane) * DIMSZ + kc * 8;
  u16* dA0 = &lA[kc * 1024 + lane * 8];         // contiguous per wave
  u16* dA1 = &lA[kc * 1024 + (lane + 64) * 8];
  u16* dB1 = &lB1[kc * 512 + lane * 8];
  u16* dB3 = &lB3[kc * 512 + lane * 8];

  for (int kt = 0; kt < DIMSZ / 32; kt++) {
    uint4 vA0 = *(const uint4*)gA0;
    uint4 vA1 = *(const uint4*)gA1;
    uint4 vB1 = *(const uint4*)gB1;
    uint4 vB3 = *(const uint4*)gB3;
    gA0 += 32; gA1 += 32; gB1 += 32; gB3 += 32;
    *(uint4*)dA0 = vA0;
    *(uint4*)dA1 = vA1;
    *(uint4*)dB1 = vB1;
    *(uint4*)dB3 = vB3;
    __syncthreads();
    bf16x8 af[4];
#pragma unroll
    for (int i = 0; i < 4; i++)
      af[i] = *(const bf16x8*)&lA[q * 1024 + (wy * 64 + i * 16 + lm) * 8];
    bf16x8 b1f[2], b3f[2];
#pragma unroll
    for (int j = 0; j < 2; j++) {
      int col = wx * 32 + j * 16 + lm;
      b1f[j] = *(const bf16x8*)&lB1[q * 512 + col * 8];
      b3f[j] = *(const bf16x8*)&lB3[q * 512 + col * 8];
    }
#pragma unroll
    for (int i = 0; i < 4; i++)
#pragma unroll
      for (int j = 0; j < 2; j++) {
        acc1[i][j] = __builtin_amdgcn_mfma_f32_16x16x32_bf16(af[i], b1f[j], acc1[i][j], 0, 0, 0);
        acc3[i][j] = __builtin_amdgcn_mfma_f32_16x16x32_bf16(af[i], b3f[j], acc3[i][j], 0, 0, 0);
      }
    __syncthreads();
  }
#pragma unroll
  for (int i = 0; i < 4; i++) {
    int rowb = mbase + wy * 64 + i * 16 + q * 4;
#pragma unroll
    for (int j = 0; j < 2; j++) {
      int col = nbase + wx * 32 + j * 16 + lm;
      f32x4 g1 = acc1[i][j], g3 = acc3[i][j];
#pragma unroll
      for (int rr = 0; rr < 4; rr++) {
        int grow = rowb + rr;
        if (grow < scnt)
          Hp[(size_t)(soff + grow) * HIDSZ + col] = f2bf(silu_f(g1[rr]) * g3[rr]);
      }
    }
  }
}

// ---------------- GEMM2: Out = (A @ W^T) * scale, BM=128 BN=128 BK=32 --------
// z<NE: routed (Orb bf16, scale=slot_score). z==NE: shared (d_out f32).
__global__ __launch_bounds__(256) void gemm2_kernel(
    const u16* __restrict__ A, const u16* __restrict__ W, u16* __restrict__ OutB,
    const u16* __restrict__ As, const u16* __restrict__ SW, float* __restrict__ OutF,
    const float* __restrict__ scale, const int* __restrict__ seg_off,
    const int* __restrict__ seg_cnt) {
  int z = blockIdx.z;
  const u16 *Ap, *wp;
  int soff, scnt;
  if (z < NE) {
    soff = seg_off[z]; scnt = seg_cnt[z];
    Ap = A; wp = W + (size_t)z * DIMSZ * HIDSZ;
  } else {
    soff = 0; scnt = T_TOK;
    Ap = As; wp = SW;
  }
  int mbase = blockIdx.y * 128;
  if (mbase >= scnt) return;
  int nbase = blockIdx.x * 128;

  __shared__ u16 lA[4 * 128 * 8];
  __shared__ u16 lB[4 * 128 * 8];

  int tid = threadIdx.x;
  int lane = tid & 63;
  int kc = tid >> 6;
  int wy = kc >> 1, wx = kc & 1;
  int q = lane >> 4, lm = lane & 15;

  f32x4 acc[4][4];
#pragma unroll
  for (int i = 0; i < 4; i++)
#pragma unroll
    for (int j = 0; j < 4; j++) acc[i][j] = (f32x4)0.f;

  int rg0 = min(mbase + lane, scnt - 1);
  int rg1 = min(mbase + 64 + lane, scnt - 1);
  const u16* gA0 = Ap + (size_t)(soff + rg0) * HIDSZ + kc * 8;
  const u16* gA1 = Ap + (size_t)(soff + rg1) * HIDSZ + kc * 8;
  const u16* gB0 = wp + (size_t)(nbase + lane) * HIDSZ + kc * 8;
  const u16* gB1 = wp + (size_t)(nbase + 64 + lane) * HIDSZ + kc * 8;
  u16* dA0 = &lA[kc * 1024 + lane * 8];
  u16* dA1 = &lA[kc * 1024 + (lane + 64) * 8];
  u16* dB0 = &lB[kc * 1024 + lane * 8];
  u16* dB1 = &lB[kc * 1024 + (lane + 64) * 8];

  for (int kt = 0; kt < HIDSZ / 32; kt++) {
    uint4 vA0 = *(const uint4*)gA0;
    uint4 vA1 = *(const uint4*)gA1;
    uint4 vB0 = *(const uint4*)gB0;
    uint4 vB1 = *(const uint4*)gB1;
    gA0 += 32; gA1 += 32; gB0 += 32; gB1 += 32;
    *(uint4*)dA0 = vA0;
    *(uint4*)dA1 = vA1;
    *(uint4*)dB0 = vB0;
    *(uint4*)dB1 = vB1;
    __syncthreads();
    bf16x8 af[4], bf[4];
#pragma unroll
    for (int i = 0; i < 4; i++) {
      af[i] = *(const bf16x8*)&lA[q * 1024 + (wy * 64 + i * 16 + lm) * 8];
      bf[i] = *(const bf16x8*)&lB[q * 1024 + (wx * 64 + i * 16 + lm) * 8];
    }
#pragma unroll
    for (int i = 0; i < 4; i++)
#pragma unroll
      for (int j = 0; j < 4; j++)
        acc[i][j] = __builtin_amdgcn_mfma_f32_16x16x32_bf16(af[i], bf[j], acc[i][j], 0, 0, 0);
    __syncthreads();
  }
#pragma unroll
  for (int i = 0; i < 4; i++) {
    int rowb = mbase + wy * 64 + i * 16 + q * 4;
#pragma unroll
    for (int j = 0; j < 4; j++) {
      int col = nbase + wx * 64 + j * 16 + lm;
      f32x4 a = acc[i][j];
#pragma unroll
      for (int rr = 0; rr < 4; rr++) {
        int grow = rowb + rr;
        if (grow < scnt) {
          size_t idx = (size_t)(soff + grow) * DIMSZ + col;
          if (z < NE) {
            OutB[idx] = f2bf(a[rr] * scale[soff + grow]);
          } else {
            OutF[idx] = a[rr];
          }
        }
      }
    }
  }
}

// ---------------- combine: out[t] += Or[pos(t,0)] + Or[pos(t,1)] -------------
__global__ __launch_bounds__(256) void combine_kernel(
    float* __restrict__ out, const u16* __restrict__ Orb,
    const int* __restrict__ slot2pos) {
  int t = blockIdx.x;
  int d = threadIdx.x * 4;
  int p0 = slot2pos[t * 2];
  int p1 = slot2pos[t * 2 + 1];
  float4 o = *(float4*)&out[(size_t)t * DIMSZ + d];
  uint2 a = *(const uint2*)&Orb[(size_t)p0 * DIMSZ + d];
  uint2 b = *(const uint2*)&Orb[(size_t)p1 * DIMSZ + d];
  o.x += bflo(a.x) + bflo(b.x);
  o.y += bfhi(a.x) + bfhi(b.x);
  o.z += bflo(a.y) + bflo(b.y);
  o.w += bfhi(a.y) + bfhi(b.y);
  *(float4*)&out[(size_t)t * DIMSZ + d] = o;
}

extern "C" void kernel_launch(void* const* d_in, const int* in_sizes, int n_in,
                              void* d_out, int out_size, void* d_ws, size_t ws_size,
                              hipStream_t stream) {
  const float* x = (const float*)d_in[0];
  const float* gw = (const float*)d_in[1];
  const float* w1 = (const float*)d_in[2];
  const float* w2 = (const float*)d_in[3];
  const float* w3 = (const float*)d_in[4];
  const float* sw1 = (const float*)d_in[5];
  const float* sw2 = (const float*)d_in[6];
  const float* sw3 = (const float*)d_in[7];
  const float* bias = (const float*)d_in[8];
  float* out = (float*)d_out;

  uint8_t* ws = (uint8_t*)d_ws;
  size_t off = 0;
  auto alloc = [&](size_t b) { size_t o = off; off += (b + 255) & ~(size_t)255; return o; };

  size_t ctrl = alloc(256);
  int* counts = (int*)(ws + ctrl);
  int* offsets = counts + 16;
  int* sel = (int*)(ws + alloc((size_t)NSLOT * 4));
  float* selscore = (float*)(ws + alloc((size_t)NSLOT * 4));
  float* slot_score = (float*)(ws + alloc((size_t)NSLOT * 4));
  int* slot2pos = (int*)(ws + alloc((size_t)NSLOT * 4));
  u16* xb = (u16*)(ws + alloc((size_t)T_TOK * DIMSZ * 2));
  u16* routed = (u16*)(ws + alloc((size_t)NSLOT * DIMSZ * 2));
  u16* Hbuf = (u16*)(ws + alloc((size_t)NSLOT * HIDSZ * 2));
  u16* Orb = (u16*)(ws + alloc((size_t)NSLOT * DIMSZ * 2));
  u16* Hs = (u16*)(ws + alloc((size_t)T_TOK * HIDSZ * 2));
  u16* w1b = (u16*)(ws + alloc((size_t)NE * HIDSZ * DIMSZ * 2));
  u16* w2b = (u16*)(ws + alloc((size_t)NE * DIMSZ * HIDSZ * 2));
  u16* w3b = (u16*)(ws + alloc((size_t)NE * HIDSZ * DIMSZ * 2));
  u16* sw1b = (u16*)(ws + alloc((size_t)HIDSZ * DIMSZ * 2));
  u16* sw2b = (u16*)(ws + alloc((size_t)DIMSZ * HIDSZ * 2));
  u16* sw3b = (u16*)(ws + alloc((size_t)HIDSZ * DIMSZ * 2));

  // weight conversion (fp32 -> bf16)
  convert3_kernel<<<dim3(2048, 3), 256, 0, stream>>>(
      w1, w2, w3, w1b, w2b, w3b, NE * HIDSZ * DIMSZ / 4);
  convert3_kernel<<<dim3(512, 3), 256, 0, stream>>>(
      sw1, sw2, sw3, sw1b, sw2b, sw3b, HIDSZ * DIMSZ / 4);

  router_kernel<<<T_TOK / 4, 256, 0, stream>>>(x, gw, bias, sel, selscore, xb);
  rank_kernel<<<1, 1024, 0, stream>>>(sel, selscore, slot2pos, slot_score,
                                      counts, offsets);
  gather_kernel<<<NSLOT / 4, 256, 0, stream>>>(x, selscore, slot2pos, routed);

  // unified GEMMs: z = 0..7 routed experts, z = 8 shared expert
  dual_glu_gemm<<<dim3(16, 64, NE + 1), 256, 0, stream>>>(
      routed, w1b, w3b, Hbuf, xb, sw1b, sw3b, Hs, offsets, counts);
  gemm2_kernel<<<dim3(8, 64, NE + 1), 256, 0, stream>>>(
      Hbuf, w2b, Orb, Hs, sw2b, out, slot_score, offsets, counts);

  // combine routed contributions into shared output
  combine_kernel<<<T_TOK, 256, 0, stream>>>(out, Orb, slot2pos);
}

// Round 7
// 541.696 us; speedup vs baseline: 1.2176x; 1.2176x over previous
//
#include <hip/hip_runtime.h>
#include <stdint.h>

typedef unsigned short u16;
typedef unsigned int u32;

#define T_TOK 8192      // B*S tokens
#define DIMSZ 1024
#define HIDSZ 1024
#define NE 8
#define NSLOT (T_TOK * 2)
#define NPAD (NSLOT + 1024)   // segment-aligned slot capacity

typedef __attribute__((ext_vector_type(8))) __bf16 bf16x8;
typedef __attribute__((ext_vector_type(4))) float f32x4;

// ---- blocked tile layouts (all GEMM operands, K = 1024, KT = 32) ----------
// A (activations, 128-row tiles):  [mt][kt][kc][row(128)][8]  (8 KB / tile)
// W (weights, 64-row tiles):       [nt][kt][kc][col(64)][8]   (4 KB / tile)
// Staging a tile = flat memcpy: global tile bytes == LDS tile bytes.
__device__ __forceinline__ size_t ablk(int pos, int c) {
  return ((((size_t)(pos >> 7) * 32 + (c >> 5)) * 4 + ((c >> 3) & 3)) * 128 +
          (pos & 127)) * 8 + (c & 7);
}

__device__ __forceinline__ u16 f2bf(float f) {
  u32 u = __builtin_bit_cast(u32, f);
  u += 0x7FFFu + ((u >> 16) & 1u);   // RNE
  return (u16)(u >> 16);
}
__device__ __forceinline__ float bflo(u32 v) { return __builtin_bit_cast(float, v << 16); }
__device__ __forceinline__ float bfhi(u32 v) { return __builtin_bit_cast(float, v & 0xffff0000u); }
__device__ __forceinline__ u32 pack2(float a, float b) {
  return (u32)f2bf(a) | ((u32)f2bf(b) << 16);
}
__device__ __forceinline__ float silu_f(float v) { return v / (1.f + expf(-v)); }

// ---------------- weight convert: fp32 row-major -> bf16 blocked ------------
// one block per 64x32 tile; LDS transpose; reads & writes fully coalesced.
__global__ __launch_bounds__(256) void convert_blocked(
    const float* __restrict__ s0, const float* __restrict__ s1,
    const float* __restrict__ s2, u16* __restrict__ d0, u16* __restrict__ d1,
    u16* __restrict__ d2) {
  const float* s = (blockIdx.y == 0) ? s0 : (blockIdx.y == 1) ? s1 : s2;
  u16* d = (blockIdx.y == 0) ? d0 : (blockIdx.y == 1) ? d1 : d2;
  __shared__ u16 lt[2048];
  int t = blockIdx.x;
  int rt = t >> 5, kt = t & 31;           // 64-row group, k-tile
  const float* sp = s + (size_t)rt * 64 * 1024 + kt * 32;
  int nl = threadIdx.x >> 2, k0 = (threadIdx.x & 3) * 8;
  float4 a = *(const float4*)(sp + (size_t)nl * 1024 + k0);
  float4 b = *(const float4*)(sp + (size_t)nl * 1024 + k0 + 4);
  uint4 p;
  p.x = pack2(a.x, a.y); p.y = pack2(a.z, a.w);
  p.z = pack2(b.x, b.y); p.w = pack2(b.z, b.w);
  *(uint4*)&lt[(threadIdx.x & 3) * 512 + nl * 8] = p;   // [kc][col][8]
  __syncthreads();
  *(uint4*)(d + (size_t)t * 2048 + threadIdx.x * 8) = *(const uint4*)&lt[threadIdx.x * 8];
}

// ---------------- router: fp32 scores, top-2; emits blocked bf16(x) ----------
__global__ __launch_bounds__(256) void router_kernel(
    const float* __restrict__ x, const float* __restrict__ gw,
    const float* __restrict__ bias, int* __restrict__ sel,
    float* __restrict__ selscore, u16* __restrict__ xb) {
  int t = blockIdx.x * 4 + (threadIdx.x >> 6);
  int lane = threadIdx.x & 63;
  float a[NE];
#pragma unroll
  for (int e = 0; e < NE; e++) a[e] = 0.f;
#pragma unroll
  for (int j = 0; j < 4; j++) {
    int c = j * 256 + lane * 4;
    float4 xv = *(const float4*)&x[(size_t)t * DIMSZ + c];
    uint2 p;
    p.x = pack2(xv.x, xv.y);
    p.y = pack2(xv.z, xv.w);
    *(uint2*)&xb[ablk(t, c)] = p;
#pragma unroll
    for (int e = 0; e < NE; e++) {
      float4 gv = *(const float4*)&gw[e * DIMSZ + c];
      a[e] = fmaf(xv.x, gv.x, fmaf(xv.y, gv.y, fmaf(xv.z, gv.z, fmaf(xv.w, gv.w, a[e]))));
    }
  }
#pragma unroll
  for (int off = 1; off < 64; off <<= 1)
#pragma unroll
    for (int e = 0; e < NE; e++) a[e] += __shfl_xor(a[e], off);
  if (lane == 0) {
    float s[NE], b[NE];
#pragma unroll
    for (int e = 0; e < NE; e++) {
      s[e] = 1.f / (1.f + expf(-a[e]));
      b[e] = s[e] + bias[e];
    }
    int e1 = 0; float v1 = b[0];
#pragma unroll
    for (int e = 1; e < NE; e++) if (b[e] > v1) { v1 = b[e]; e1 = e; }
    int e2 = -1; float v2 = -1e30f;
#pragma unroll
    for (int e = 0; e < NE; e++) if (e != e1 && b[e] > v2) { v2 = b[e]; e2 = e; }
    sel[t * 2] = e1; sel[t * 2 + 1] = e2;
    selscore[t * 2] = s[e1];       // ROUTE_SCALE == 1
    selscore[t * 2 + 1] = s[e2];
  }
}

// ---------------- rank: atomic-free permutation; 128-aligned segments --------
__global__ __launch_bounds__(1024) void rank_kernel(
    const int* __restrict__ sel, const float* __restrict__ selscore,
    int* __restrict__ slot2pos, float* __restrict__ slot_score,
    int* __restrict__ counts, int* __restrict__ offsets) {
  __shared__ int hist[NE * 1024];
  __shared__ int tot[NE];
  __shared__ int offs[NE];
  int tid = threadIdx.x;
  int sl[16];
  int h[NE];
#pragma unroll
  for (int e = 0; e < NE; e++) h[e] = 0;
#pragma unroll
  for (int j = 0; j < 4; j++) {
    int4 v = ((const int4*)sel)[tid * 4 + j];
    sl[j * 4 + 0] = v.x; sl[j * 4 + 1] = v.y;
    sl[j * 4 + 2] = v.z; sl[j * 4 + 3] = v.w;
  }
#pragma unroll
  for (int i = 0; i < 16; i++)
#pragma unroll
    for (int e = 0; e < NE; e++) h[e] += (sl[i] == e) ? 1 : 0;
#pragma unroll
  for (int e = 0; e < NE; e++) hist[e * 1024 + tid] = h[e];
  __syncthreads();
  int wid = tid >> 6, lane = tid & 63;
  if (wid < NE) {
    int e = wid;
    int vals[16];
    int lsum = 0;
#pragma unroll
    for (int i = 0; i < 16; i++) {
      int v = hist[e * 1024 + lane * 16 + i];
      vals[i] = lsum;
      lsum += v;
    }
    int incl = lsum;
#pragma unroll
    for (int off = 1; off < 64; off <<= 1) {
      int v = __shfl_up(incl, off);
      if (lane >= off) incl += v;
    }
    int excl = incl - lsum;
#pragma unroll
    for (int i = 0; i < 16; i++) hist[e * 1024 + lane * 16 + i] = vals[i] + excl;
    if (lane == 63) tot[e] = incl;
  }
  __syncthreads();
  if (tid == 0) {
    int acc = 0;
    for (int e = 0; e < NE; e++) {
      offs[e] = acc;
      offsets[e] = acc;
      counts[e] = tot[e];
      acc += (tot[e] + 127) & ~127;   // 128-align every segment
    }
  }
  __syncthreads();
  int base[NE];
#pragma unroll
  for (int e = 0; e < NE; e++) base[e] = offs[e] + hist[e * 1024 + tid];
#pragma unroll
  for (int i = 0; i < 16; i++) {
    int slot = tid * 16 + i;
    int e = sl[i];
    int pos = 0;
#pragma unroll
    for (int k = 0; k < NE; k++) pos += (e == k) ? base[k] : 0;
#pragma unroll
    for (int k = 0; k < NE; k++) base[k] += (e == k) ? 1 : 0;
    slot2pos[slot] = pos;
    slot_score[pos] = selscore[slot];
  }
}

// ---------------- gather: slot -> blocked row pos of bf16(s*x) ---------------
__global__ __launch_bounds__(256) void gather_kernel(
    const float* __restrict__ x, const float* __restrict__ selscore,
    const int* __restrict__ slot2pos, u16* __restrict__ routed) {
  int s = blockIdx.x * 4 + (threadIdx.x >> 6);
  int lane = threadIdx.x & 63;
  int pos = slot2pos[s];
  float sc = selscore[s];
  int t = s >> 1;
#pragma unroll
  for (int j = 0; j < 4; j++) {
    int c = j * 256 + lane * 4;
    float4 v = *(const float4*)&x[(size_t)t * DIMSZ + c];
    uint2 p;
    p.x = pack2(v.x * sc, v.y * sc);
    p.y = pack2(v.z * sc, v.w * sc);
    *(uint2*)&routed[ablk(pos, c)] = p;
  }
}

// ---------------- dual GEMM (G1,G3 share A-tile) + silu*mul -> H (blocked) ---
// BM=128 BN=64 BK=32. Staging = flat tile memcpy (coalesced + conflict-free).
__global__ __launch_bounds__(256) void dual_glu_gemm(
    const u16* __restrict__ A, const u16* __restrict__ W1,
    const u16* __restrict__ W3, u16* __restrict__ Hout,
    const u16* __restrict__ As, const u16* __restrict__ SW1,
    const u16* __restrict__ SW3, u16* __restrict__ Hs,
    const int* __restrict__ seg_off, const int* __restrict__ seg_cnt) {
  int z = blockIdx.z;
  const u16 *Ap, *w1p, *w3p;
  u16* Hp;
  int soff, scnt;
  if (z < NE) {
    soff = seg_off[z]; scnt = seg_cnt[z];
    Ap = A;
    w1p = W1 + (size_t)z * HIDSZ * DIMSZ;
    w3p = W3 + (size_t)z * HIDSZ * DIMSZ;
    Hp = Hout;
  } else {
    soff = 0; scnt = T_TOK;
    Ap = As; w1p = SW1; w3p = SW3;
    Hp = Hs;
  }
  int mbase = blockIdx.y * 128;
  if (mbase >= scnt) return;
  int nbase = blockIdx.x * 64;

  __shared__ u16 lA[4096];   // [kc][row128][8]
  __shared__ u16 lB1[2048];  // [kc][col64][8]
  __shared__ u16 lB3[2048];

  int tid = threadIdx.x;
  int lane = tid & 63;
  int wid = tid >> 6;
  int wy = wid >> 1, wx = wid & 1;
  int q = lane >> 4, lm = lane & 15;

  f32x4 acc1[4][2], acc3[4][2];
#pragma unroll
  for (int i = 0; i < 4; i++)
#pragma unroll
    for (int j = 0; j < 2; j++) { acc1[i][j] = (f32x4)0.f; acc3[i][j] = (f32x4)0.f; }

  const u16* gA = Ap + ((size_t)((soff + mbase) >> 7) * 32) * 4096 + tid * 8;
  const u16* gB1 = w1p + ((size_t)(nbase >> 6) * 32) * 2048 + tid * 8;
  const u16* gB3 = w3p + ((size_t)(nbase >> 6) * 32) * 2048 + tid * 8;

  for (int kt = 0; kt < DIMSZ / 32; kt++) {
    uint4 vA0 = *(const uint4*)gA;
    uint4 vA1 = *(const uint4*)(gA + 2048);
    uint4 v1 = *(const uint4*)gB1;
    uint4 v3 = *(const uint4*)gB3;
    gA += 4096; gB1 += 2048; gB3 += 2048;
    *(uint4*)&lA[tid * 8] = vA0;
    *(uint4*)&lA[2048 + tid * 8] = vA1;
    *(uint4*)&lB1[tid * 8] = v1;
    *(uint4*)&lB3[tid * 8] = v3;
    __syncthreads();
    bf16x8 af[4];
#pragma unroll
    for (int i = 0; i < 4; i++)
      af[i] = *(const bf16x8*)&lA[(q * 128 + wy * 64 + i * 16 + lm) * 8];
    bf16x8 b1f[2], b3f[2];
#pragma unroll
    for (int j = 0; j < 2; j++) {
      int col = wx * 32 + j * 16 + lm;
      b1f[j] = *(const bf16x8*)&lB1[(q * 64 + col) * 8];
      b3f[j] = *(const bf16x8*)&lB3[(q * 64 + col) * 8];
    }
#pragma unroll
    for (int i = 0; i < 4; i++)
#pragma unroll
      for (int j = 0; j < 2; j++) {
        acc1[i][j] = __builtin_amdgcn_mfma_f32_16x16x32_bf16(af[i], b1f[j], acc1[i][j], 0, 0, 0);
        acc3[i][j] = __builtin_amdgcn_mfma_f32_16x16x32_bf16(af[i], b3f[j], acc3[i][j], 0, 0, 0);
      }
    __syncthreads();
  }
#pragma unroll
  for (int i = 0; i < 4; i++) {
    int rowb = mbase + wy * 64 + i * 16 + q * 4;
#pragma unroll
    for (int j = 0; j < 2; j++) {
      int col = nbase + wx * 32 + j * 16 + lm;
      f32x4 g1 = acc1[i][j], g3 = acc3[i][j];
#pragma unroll
      for (int rr = 0; rr < 4; rr++) {
        int grow = rowb + rr;
        if (grow < scnt)
          Hp[ablk(soff + grow, col)] = f2bf(silu_f(g1[rr]) * g3[rr]);
      }
    }
  }
}

// ---------------- GEMM2: Out = (A @ W^T) * scale, BM=128 BN=128 BK=32 --------
__global__ __launch_bounds__(256) void gemm2_kernel(
    const u16* __restrict__ A, const u16* __restrict__ W, u16* __restrict__ OutB,
    const u16* __restrict__ As, const u16* __restrict__ SW, float* __restrict__ OutF,
    const float* __restrict__ scale, const int* __restrict__ seg_off,
    const int* __restrict__ seg_cnt) {
  int z = blockIdx.z;
  const u16 *Ap, *wp;
  int soff, scnt;
  if (z < NE) {
    soff = seg_off[z]; scnt = seg_cnt[z];
    Ap = A; wp = W + (size_t)z * DIMSZ * HIDSZ;
  } else {
    soff = 0; scnt = T_TOK;
    Ap = As; wp = SW;
  }
  int mbase = blockIdx.y * 128;
  if (mbase >= scnt) return;
  int nbase = blockIdx.x * 128;

  __shared__ u16 lA[4096];   // [kc][row128][8]
  __shared__ u16 lB[4096];   // [half][kc][col64][8]

  int tid = threadIdx.x;
  int lane = tid & 63;
  int wid = tid >> 6;
  int wy = wid >> 1, wx = wid & 1;
  int q = lane >> 4, lm = lane & 15;

  f32x4 acc[4][4];
#pragma unroll
  for (int i = 0; i < 4; i++)
#pragma unroll
    for (int j = 0; j < 4; j++) acc[i][j] = (f32x4)0.f;

  const u16* gA = Ap + ((size_t)((soff + mbase) >> 7) * 32) * 4096 + tid * 8;
  const u16* gB0 = wp + ((size_t)(nbase >> 6) * 32) * 2048 + tid * 8;
  const u16* gB1 = wp + ((size_t)((nbase >> 6) + 1) * 32) * 2048 + tid * 8;

  for (int kt = 0; kt < HIDSZ / 32; kt++) {
    uint4 vA0 = *(const uint4*)gA;
    uint4 vA1 = *(const uint4*)(gA + 2048);
    uint4 vB0 = *(const uint4*)gB0;
    uint4 vB1 = *(const uint4*)gB1;
    gA += 4096; gB0 += 2048; gB1 += 2048;
    *(uint4*)&lA[tid * 8] = vA0;
    *(uint4*)&lA[2048 + tid * 8] = vA1;
    *(uint4*)&lB[tid * 8] = vB0;
    *(uint4*)&lB[2048 + tid * 8] = vB1;
    __syncthreads();
    bf16x8 af[4], bf[4];
#pragma unroll
    for (int i = 0; i < 4; i++) {
      af[i] = *(const bf16x8*)&lA[(q * 128 + wy * 64 + i * 16 + lm) * 8];
      bf[i] = *(const bf16x8*)&lB[wx * 2048 + (q * 64 + i * 16 + lm) * 8];
    }
#pragma unroll
    for (int i = 0; i < 4; i++)
#pragma unroll
      for (int j = 0; j < 4; j++)
        acc[i][j] = __builtin_amdgcn_mfma_f32_16x16x32_bf16(af[i], bf[j], acc[i][j], 0, 0, 0);
    __syncthreads();
  }
#pragma unroll
  for (int i = 0; i < 4; i++) {
    int rowb = mbase + wy * 64 + i * 16 + q * 4;
#pragma unroll
    for (int j = 0; j < 4; j++) {
      int col = nbase + wx * 64 + j * 16 + lm;
      f32x4 a = acc[i][j];
#pragma unroll
      for (int rr = 0; rr < 4; rr++) {
        int grow = rowb + rr;
        if (grow < scnt) {
          size_t idx = (size_t)(soff + grow) * DIMSZ + col;
          if (z < NE) {
            OutB[idx] = f2bf(a[rr] * scale[soff + grow]);
          } else {
            OutF[idx] = a[rr];
          }
        }
      }
    }
  }
}

// ---------------- combine: out[t] += Or[pos(t,0)] + Or[pos(t,1)] -------------
__global__ __launch_bounds__(256) void combine_kernel(
    float* __restrict__ out, const u16* __restrict__ Orb,
    const int* __restrict__ slot2pos) {
  int t = blockIdx.x;
  int d = threadIdx.x * 4;
  int p0 = slot2pos[t * 2];
  int p1 = slot2pos[t * 2 + 1];
  float4 o = *(float4*)&out[(size_t)t * DIMSZ + d];
  uint2 a = *(const uint2*)&Orb[(size_t)p0 * DIMSZ + d];
  uint2 b = *(const uint2*)&Orb[(size_t)p1 * DIMSZ + d];
  o.x += bflo(a.x) + bflo(b.x);
  o.y += bfhi(a.x) + bfhi(b.x);
  o.z += bflo(a.y) + bflo(b.y);
  o.w += bfhi(a.y) + bfhi(b.y);
  *(float4*)&out[(size_t)t * DIMSZ + d] = o;
}

extern "C" void kernel_launch(void* const* d_in, const int* in_sizes, int n_in,
                              void* d_out, int out_size, void* d_ws, size_t ws_size,
                              hipStream_t stream) {
  const float* x = (const float*)d_in[0];
  const float* gw = (const float*)d_in[1];
  const float* w1 = (const float*)d_in[2];
  const float* w2 = (const float*)d_in[3];
  const float* w3 = (const float*)d_in[4];
  const float* sw1 = (const float*)d_in[5];
  const float* sw2 = (const float*)d_in[6];
  const float* sw3 = (const float*)d_in[7];
  const float* bias = (const float*)d_in[8];
  float* out = (float*)d_out;

  uint8_t* ws = (uint8_t*)d_ws;
  size_t off = 0;
  auto alloc = [&](size_t b) { size_t o = off; off += (b + 255) & ~(size_t)255; return o; };

  size_t ctrl = alloc(256);
  int* counts = (int*)(ws + ctrl);
  int* offsets = counts + 16;
  int* sel = (int*)(ws + alloc((size_t)NSLOT * 4));
  float* selscore = (float*)(ws + alloc((size_t)NSLOT * 4));
  float* slot_score = (float*)(ws + alloc((size_t)NPAD * 4));
  int* slot2pos = (int*)(ws + alloc((size_t)NSLOT * 4));
  u16* xb = (u16*)(ws + alloc((size_t)T_TOK * DIMSZ * 2));
  u16* routed = (u16*)(ws + alloc((size_t)NPAD * DIMSZ * 2));
  u16* Hbuf = (u16*)(ws + alloc((size_t)NPAD * HIDSZ * 2));
  u16* Orb = (u16*)(ws + alloc((size_t)NPAD * DIMSZ * 2));
  u16* Hs = (u16*)(ws + alloc((size_t)T_TOK * HIDSZ * 2));
  u16* w1b = (u16*)(ws + alloc((size_t)NE * HIDSZ * DIMSZ * 2));
  u16* w2b = (u16*)(ws + alloc((size_t)NE * DIMSZ * HIDSZ * 2));
  u16* w3b = (u16*)(ws + alloc((size_t)NE * HIDSZ * DIMSZ * 2));
  u16* sw1b = (u16*)(ws + alloc((size_t)HIDSZ * DIMSZ * 2));
  u16* sw2b = (u16*)(ws + alloc((size_t)DIMSZ * HIDSZ * 2));
  u16* sw3b = (u16*)(ws + alloc((size_t)HIDSZ * DIMSZ * 2));

  // weight conversion fp32 row-major -> bf16 blocked tiles
  convert_blocked<<<dim3(NE * 16 * 32, 3), 256, 0, stream>>>(
      w1, w2, w3, w1b, w2b, w3b);
  convert_blocked<<<dim3(16 * 32, 3), 256, 0, stream>>>(
      sw1, sw2, sw3, sw1b, sw2b, sw3b);

  router_kernel<<<T_TOK / 4, 256, 0, stream>>>(x, gw, bias, sel, selscore, xb);
  rank_kernel<<<1, 1024, 0, stream>>>(sel, selscore, slot2pos, slot_score,
                                      counts, offsets);
  gather_kernel<<<NSLOT / 4, 256, 0, stream>>>(x, selscore, slot2pos, routed);

  // unified GEMMs: z = 0..7 routed experts, z = 8 shared expert
  dual_glu_gemm<<<dim3(16, 64, NE + 1), 256, 0, stream>>>(
      routed, w1b, w3b, Hbuf, xb, sw1b, sw3b, Hs, offsets, counts);
  gemm2_kernel<<<dim3(8, 64, NE + 1), 256, 0, stream>>>(
      Hbuf, w2b, Orb, Hs, sw2b, out, slot_score, offsets, counts);

  // combine routed contributions into shared output
  combine_kernel<<<T_TOK, 256, 0, stream>>>(out, Orb, slot2pos);
}

// Round 8
// 524.695 us; speedup vs baseline: 1.2570x; 1.0324x over previous
//
#include <hip/hip_runtime.h>
#include <stdint.h>

typedef unsigned short u16;
typedef unsigned int u32;

#define T_TOK 8192      // B*S tokens
#define DIMSZ 1024
#define HIDSZ 1024
#define NE 8
#define NSLOT (T_TOK * 2)
#define NPAD (NSLOT + 1024)   // segment-aligned slot capacity

typedef __attribute__((ext_vector_type(8))) __bf16 bf16x8;
typedef __attribute__((ext_vector_type(4))) float f32x4;

// ---- blocked tile layouts (all GEMM operands, K = 1024, KT = 32) ----------
// A (activations, 128-row tiles):  [mt][kt][kc][row(128)][8]  (8 KB / tile)
// W (weights, 64-row tiles):       [nt][kt][kc][col(64)][8]   (4 KB / tile)
// Staging a tile = flat memcpy: global tile bytes == LDS tile bytes.
__device__ __forceinline__ size_t ablk(int pos, int c) {
  return ((((size_t)(pos >> 7) * 32 + (c >> 5)) * 4 + ((c >> 3) & 3)) * 128 +
          (pos & 127)) * 8 + (c & 7);
}

__device__ __forceinline__ u16 f2bf(float f) {
  u32 u = __builtin_bit_cast(u32, f);
  u += 0x7FFFu + ((u >> 16) & 1u);   // RNE
  return (u16)(u >> 16);
}
__device__ __forceinline__ float bflo(u32 v) { return __builtin_bit_cast(float, v << 16); }
__device__ __forceinline__ float bfhi(u32 v) { return __builtin_bit_cast(float, v & 0xffff0000u); }
__device__ __forceinline__ u32 pack2(float a, float b) {
  return (u32)f2bf(a) | ((u32)f2bf(b) << 16);
}
__device__ __forceinline__ float silu_f(float v) { return v / (1.f + expf(-v)); }

// ---------------- weight convert: fp32 row-major -> bf16 blocked ------------
__global__ __launch_bounds__(256) void convert_blocked(
    const float* __restrict__ s0, const float* __restrict__ s1,
    const float* __restrict__ s2, u16* __restrict__ d0, u16* __restrict__ d1,
    u16* __restrict__ d2) {
  const float* s = (blockIdx.y == 0) ? s0 : (blockIdx.y == 1) ? s1 : s2;
  u16* d = (blockIdx.y == 0) ? d0 : (blockIdx.y == 1) ? d1 : d2;
  __shared__ u16 lt[2048];
  int t = blockIdx.x;
  int rt = t >> 5, kt = t & 31;           // 64-row group, k-tile
  const float* sp = s + (size_t)rt * 64 * 1024 + kt * 32;
  int nl = threadIdx.x >> 2, k0 = (threadIdx.x & 3) * 8;
  float4 a = *(const float4*)(sp + (size_t)nl * 1024 + k0);
  float4 b = *(const float4*)(sp + (size_t)nl * 1024 + k0 + 4);
  uint4 p;
  p.x = pack2(a.x, a.y); p.y = pack2(a.z, a.w);
  p.z = pack2(b.x, b.y); p.w = pack2(b.z, b.w);
  *(uint4*)&lt[(threadIdx.x & 3) * 512 + nl * 8] = p;   // [kc][col][8]
  __syncthreads();
  *(uint4*)(d + (size_t)t * 2048 + threadIdx.x * 8) = *(const uint4*)&lt[threadIdx.x * 8];
}

// ---------------- router: fp32 scores, top-2; emits blocked bf16(x) ----------
__global__ __launch_bounds__(256) void router_kernel(
    const float* __restrict__ x, const float* __restrict__ gw,
    const float* __restrict__ bias, int* __restrict__ sel,
    float* __restrict__ selscore, u16* __restrict__ xb) {
  int t = blockIdx.x * 4 + (threadIdx.x >> 6);
  int lane = threadIdx.x & 63;
  float a[NE];
#pragma unroll
  for (int e = 0; e < NE; e++) a[e] = 0.f;
#pragma unroll
  for (int j = 0; j < 4; j++) {
    int c = j * 256 + lane * 4;
    float4 xv = *(const float4*)&x[(size_t)t * DIMSZ + c];
    uint2 p;
    p.x = pack2(xv.x, xv.y);
    p.y = pack2(xv.z, xv.w);
    *(uint2*)&xb[ablk(t, c)] = p;
#pragma unroll
    for (int e = 0; e < NE; e++) {
      float4 gv = *(const float4*)&gw[e * DIMSZ + c];
      a[e] = fmaf(xv.x, gv.x, fmaf(xv.y, gv.y, fmaf(xv.z, gv.z, fmaf(xv.w, gv.w, a[e]))));
    }
  }
#pragma unroll
  for (int off = 1; off < 64; off <<= 1)
#pragma unroll
    for (int e = 0; e < NE; e++) a[e] += __shfl_xor(a[e], off);
  if (lane == 0) {
    float s[NE], b[NE];
#pragma unroll
    for (int e = 0; e < NE; e++) {
      s[e] = 1.f / (1.f + expf(-a[e]));
      b[e] = s[e] + bias[e];
    }
    int e1 = 0; float v1 = b[0];
#pragma unroll
    for (int e = 1; e < NE; e++) if (b[e] > v1) { v1 = b[e]; e1 = e; }
    int e2 = -1; float v2 = -1e30f;
#pragma unroll
    for (int e = 0; e < NE; e++) if (e != e1 && b[e] > v2) { v2 = b[e]; e2 = e; }
    sel[t * 2] = e1; sel[t * 2 + 1] = e2;
    selscore[t * 2] = s[e1];       // ROUTE_SCALE == 1
    selscore[t * 2 + 1] = s[e2];
  }
}

// ---------------- rank: atomic-free permutation; 128-aligned segments --------
__global__ __launch_bounds__(1024) void rank_kernel(
    const int* __restrict__ sel, const float* __restrict__ selscore,
    int* __restrict__ slot2pos, float* __restrict__ slot_score,
    int* __restrict__ counts, int* __restrict__ offsets) {
  __shared__ int hist[NE * 1024];
  __shared__ int tot[NE];
  __shared__ int offs[NE];
  int tid = threadIdx.x;
  int sl[16];
  int h[NE];
#pragma unroll
  for (int e = 0; e < NE; e++) h[e] = 0;
#pragma unroll
  for (int j = 0; j < 4; j++) {
    int4 v = ((const int4*)sel)[tid * 4 + j];
    sl[j * 4 + 0] = v.x; sl[j * 4 + 1] = v.y;
    sl[j * 4 + 2] = v.z; sl[j * 4 + 3] = v.w;
  }
#pragma unroll
  for (int i = 0; i < 16; i++)
#pragma unroll
    for (int e = 0; e < NE; e++) h[e] += (sl[i] == e) ? 1 : 0;
#pragma unroll
  for (int e = 0; e < NE; e++) hist[e * 1024 + tid] = h[e];
  __syncthreads();
  int wid = tid >> 6, lane = tid & 63;
  if (wid < NE) {
    int e = wid;
    int vals[16];
    int lsum = 0;
#pragma unroll
    for (int i = 0; i < 16; i++) {
      int v = hist[e * 1024 + lane * 16 + i];
      vals[i] = lsum;
      lsum += v;
    }
    int incl = lsum;
#pragma unroll
    for (int off = 1; off < 64; off <<= 1) {
      int v = __shfl_up(incl, off);
      if (lane >= off) incl += v;
    }
    int excl = incl - lsum;
#pragma unroll
    for (int i = 0; i < 16; i++) hist[e * 1024 + lane * 16 + i] = vals[i] + excl;
    if (lane == 63) tot[e] = incl;
  }
  __syncthreads();
  if (tid == 0) {
    int acc = 0;
    for (int e = 0; e < NE; e++) {
      offs[e] = acc;
      offsets[e] = acc;
      counts[e] = tot[e];
      acc += (tot[e] + 127) & ~127;   // 128-align every segment
    }
  }
  __syncthreads();
  int base[NE];
#pragma unroll
  for (int e = 0; e < NE; e++) base[e] = offs[e] + hist[e * 1024 + tid];
#pragma unroll
  for (int i = 0; i < 16; i++) {
    int slot = tid * 16 + i;
    int e = sl[i];
    int pos = 0;
#pragma unroll
    for (int k = 0; k < NE; k++) pos += (e == k) ? base[k] : 0;
#pragma unroll
    for (int k = 0; k < NE; k++) base[k] += (e == k) ? 1 : 0;
    slot2pos[slot] = pos;
    slot_score[pos] = selscore[slot];
  }
}

// ---------------- gather: slot -> blocked row pos of bf16(s*x) ---------------
__global__ __launch_bounds__(256) void gather_kernel(
    const float* __restrict__ x, const float* __restrict__ selscore,
    const int* __restrict__ slot2pos, u16* __restrict__ routed) {
  int s = blockIdx.x * 4 + (threadIdx.x >> 6);
  int lane = threadIdx.x & 63;
  int pos = slot2pos[s];
  float sc = selscore[s];
  int t = s >> 1;
#pragma unroll
  for (int j = 0; j < 4; j++) {
    int c = j * 256 + lane * 4;
    float4 v = *(const float4*)&x[(size_t)t * DIMSZ + c];
    uint2 p;
    p.x = pack2(v.x * sc, v.y * sc);
    p.y = pack2(v.z * sc, v.w * sc);
    *(uint2*)&routed[ablk(pos, c)] = p;
  }
}

// ---------------- dual GEMM (G1,G3 share A-tile) + silu*mul -> H (blocked) ---
// BM=128 BN=64 BK=32. Flat tile memcpy staging + single-barrier LDS dbuf:
//   store k (waits loads k) -> barrier -> issue loads k+1 -> compute k.
__global__ __launch_bounds__(256) void dual_glu_gemm(
    const u16* __restrict__ A, const u16* __restrict__ W1,
    const u16* __restrict__ W3, u16* __restrict__ Hout,
    const u16* __restrict__ As, const u16* __restrict__ SW1,
    const u16* __restrict__ SW3, u16* __restrict__ Hs,
    const int* __restrict__ seg_off, const int* __restrict__ seg_cnt) {
  int z = blockIdx.z;
  const u16 *Ap, *w1p, *w3p;
  u16* Hp;
  int soff, scnt;
  if (z < NE) {
    soff = seg_off[z]; scnt = seg_cnt[z];
    Ap = A;
    w1p = W1 + (size_t)z * HIDSZ * DIMSZ;
    w3p = W3 + (size_t)z * HIDSZ * DIMSZ;
    Hp = Hout;
  } else {
    soff = 0; scnt = T_TOK;
    Ap = As; w1p = SW1; w3p = SW3;
    Hp = Hs;
  }
  int mbase = blockIdx.y * 128;
  if (mbase >= scnt) return;
  int nbase = blockIdx.x * 64;

  __shared__ u16 lA[2][4096];   // [kc][row128][8]
  __shared__ u16 lB1[2][2048];  // [kc][col64][8]
  __shared__ u16 lB3[2][2048];

  int tid = threadIdx.x;
  int lane = tid & 63;
  int wid = tid >> 6;
  int wy = wid >> 1, wx = wid & 1;
  int q = lane >> 4, lm = lane & 15;

  f32x4 acc1[4][2], acc3[4][2];
#pragma unroll
  for (int i = 0; i < 4; i++)
#pragma unroll
    for (int j = 0; j < 2; j++) { acc1[i][j] = (f32x4)0.f; acc3[i][j] = (f32x4)0.f; }

  const u16* gA = Ap + ((size_t)((soff + mbase) >> 7) * 32) * 4096 + tid * 8;
  const u16* gB1 = w1p + ((size_t)(nbase >> 6) * 32) * 2048 + tid * 8;
  const u16* gB3 = w3p + ((size_t)(nbase >> 6) * 32) * 2048 + tid * 8;

  // preload tile 0
  uint4 rA0 = *(const uint4*)gA;
  uint4 rA1 = *(const uint4*)(gA + 2048);
  uint4 rB1 = *(const uint4*)gB1;
  uint4 rB3 = *(const uint4*)gB3;
  gA += 4096; gB1 += 2048; gB3 += 2048;

  for (int kt = 0; kt < DIMSZ / 32; kt++) {
    int buf = kt & 1;
    *(uint4*)&lA[buf][tid * 8] = rA0;
    *(uint4*)&lA[buf][2048 + tid * 8] = rA1;
    *(uint4*)&lB1[buf][tid * 8] = rB1;
    *(uint4*)&lB3[buf][tid * 8] = rB3;
    __syncthreads();
    if (kt < DIMSZ / 32 - 1) {
      rA0 = *(const uint4*)gA;
      rA1 = *(const uint4*)(gA + 2048);
      rB1 = *(const uint4*)gB1;
      rB3 = *(const uint4*)gB3;
      gA += 4096; gB1 += 2048; gB3 += 2048;
    }
    bf16x8 af[4];
#pragma unroll
    for (int i = 0; i < 4; i++)
      af[i] = *(const bf16x8*)&lA[buf][(q * 128 + wy * 64 + i * 16 + lm) * 8];
    bf16x8 b1f[2], b3f[2];
#pragma unroll
    for (int j = 0; j < 2; j++) {
      int col = wx * 32 + j * 16 + lm;
      b1f[j] = *(const bf16x8*)&lB1[buf][(q * 64 + col) * 8];
      b3f[j] = *(const bf16x8*)&lB3[buf][(q * 64 + col) * 8];
    }
#pragma unroll
    for (int i = 0; i < 4; i++)
#pragma unroll
      for (int j = 0; j < 2; j++) {
        acc1[i][j] = __builtin_amdgcn_mfma_f32_16x16x32_bf16(af[i], b1f[j], acc1[i][j], 0, 0, 0);
        acc3[i][j] = __builtin_amdgcn_mfma_f32_16x16x32_bf16(af[i], b3f[j], acc3[i][j], 0, 0, 0);
      }
  }
#pragma unroll
  for (int i = 0; i < 4; i++) {
    int rowb = mbase + wy * 64 + i * 16 + q * 4;
#pragma unroll
    for (int j = 0; j < 2; j++) {
      int col = nbase + wx * 32 + j * 16 + lm;
      f32x4 g1 = acc1[i][j], g3 = acc3[i][j];
#pragma unroll
      for (int rr = 0; rr < 4; rr++) {
        int grow = rowb + rr;
        if (grow < scnt)
          Hp[ablk(soff + grow, col)] = f2bf(silu_f(g1[rr]) * g3[rr]);
      }
    }
  }
}

// ---------------- GEMM2: Out = (A @ W^T) * scale, BM=128 BN=128 BK=32 --------
__global__ __launch_bounds__(256) void gemm2_kernel(
    const u16* __restrict__ A, const u16* __restrict__ W, u16* __restrict__ OutB,
    const u16* __restrict__ As, const u16* __restrict__ SW, float* __restrict__ OutF,
    const float* __restrict__ scale, const int* __restrict__ seg_off,
    const int* __restrict__ seg_cnt) {
  int z = blockIdx.z;
  const u16 *Ap, *wp;
  int soff, scnt;
  if (z < NE) {
    soff = seg_off[z]; scnt = seg_cnt[z];
    Ap = A; wp = W + (size_t)z * DIMSZ * HIDSZ;
  } else {
    soff = 0; scnt = T_TOK;
    Ap = As; wp = SW;
  }
  int mbase = blockIdx.y * 128;
  if (mbase >= scnt) return;
  int nbase = blockIdx.x * 128;

  __shared__ u16 lA[2][4096];   // [kc][row128][8]
  __shared__ u16 lB[2][4096];   // [half][kc][col64][8]

  int tid = threadIdx.x;
  int lane = tid & 63;
  int wid = tid >> 6;
  int wy = wid >> 1, wx = wid & 1;
  int q = lane >> 4, lm = lane & 15;

  f32x4 acc[4][4];
#pragma unroll
  for (int i = 0; i < 4; i++)
#pragma unroll
    for (int j = 0; j < 4; j++) acc[i][j] = (f32x4)0.f;

  const u16* gA = Ap + ((size_t)((soff + mbase) >> 7) * 32) * 4096 + tid * 8;
  const u16* gB0 = wp + ((size_t)(nbase >> 6) * 32) * 2048 + tid * 8;
  const u16* gB1 = wp + ((size_t)((nbase >> 6) + 1) * 32) * 2048 + tid * 8;

  uint4 rA0 = *(const uint4*)gA;
  uint4 rA1 = *(const uint4*)(gA + 2048);
  uint4 rB0 = *(const uint4*)gB0;
  uint4 rB1 = *(const uint4*)gB1;
  gA += 4096; gB0 += 2048; gB1 += 2048;

  for (int kt = 0; kt < HIDSZ / 32; kt++) {
    int buf = kt & 1;
    *(uint4*)&lA[buf][tid * 8] = rA0;
    *(uint4*)&lA[buf][2048 + tid * 8] = rA1;
    *(uint4*)&lB[buf][tid * 8] = rB0;
    *(uint4*)&lB[buf][2048 + tid * 8] = rB1;
    __syncthreads();
    if (kt < HIDSZ / 32 - 1) {
      rA0 = *(const uint4*)gA;
      rA1 = *(const uint4*)(gA + 2048);
      rB0 = *(const uint4*)gB0;
      rB1 = *(const uint4*)gB1;
      gA += 4096; gB0 += 2048; gB1 += 2048;
    }
    bf16x8 af[4], bf[4];
#pragma unroll
    for (int i = 0; i < 4; i++) {
      af[i] = *(const bf16x8*)&lA[buf][(q * 128 + wy * 64 + i * 16 + lm) * 8];
      bf[i] = *(const bf16x8*)&lB[buf][wx * 2048 + (q * 64 + i * 16 + lm) * 8];
    }
#pragma unroll
    for (int i = 0; i < 4; i++)
#pragma unroll
      for (int j = 0; j < 4; j++)
        acc[i][j] = __builtin_amdgcn_mfma_f32_16x16x32_bf16(af[i], bf[j], acc[i][j], 0, 0, 0);
  }
#pragma unroll
  for (int i = 0; i < 4; i++) {
    int rowb = mbase + wy * 64 + i * 16 + q * 4;
#pragma unroll
    for (int j = 0; j < 4; j++) {
      int col = nbase + wx * 64 + j * 16 + lm;
      f32x4 a = acc[i][j];
#pragma unroll
      for (int rr = 0; rr < 4; rr++) {
        int grow = rowb + rr;
        if (grow < scnt) {
          size_t idx = (size_t)(soff + grow) * DIMSZ + col;
          if (z < NE) {
            OutB[idx] = f2bf(a[rr] * scale[soff + grow]);
          } else {
            OutF[idx] = a[rr];
          }
        }
      }
    }
  }
}

// ---------------- combine: out[t] += Or[pos(t,0)] + Or[pos(t,1)] -------------
__global__ __launch_bounds__(256) void combine_kernel(
    float* __restrict__ out, const u16* __restrict__ Orb,
    const int* __restrict__ slot2pos) {
  int t = blockIdx.x;
  int d = threadIdx.x * 4;
  int p0 = slot2pos[t * 2];
  int p1 = slot2pos[t * 2 + 1];
  float4 o = *(float4*)&out[(size_t)t * DIMSZ + d];
  uint2 a = *(const uint2*)&Orb[(size_t)p0 * DIMSZ + d];
  uint2 b = *(const uint2*)&Orb[(size_t)p1 * DIMSZ + d];
  o.x += bflo(a.x) + bflo(b.x);
  o.y += bfhi(a.x) + bfhi(b.x);
  o.z += bflo(a.y) + bflo(b.y);
  o.w += bfhi(a.y) + bfhi(b.y);
  *(float4*)&out[(size_t)t * DIMSZ + d] = o;
}

extern "C" void kernel_launch(void* const* d_in, const int* in_sizes, int n_in,
                              void* d_out, int out_size, void* d_ws, size_t ws_size,
                              hipStream_t stream) {
  const float* x = (const float*)d_in[0];
  const float* gw = (const float*)d_in[1];
  const float* w1 = (const float*)d_in[2];
  const float* w2 = (const float*)d_in[3];
  const float* w3 = (const float*)d_in[4];
  const float* sw1 = (const float*)d_in[5];
  const float* sw2 = (const float*)d_in[6];
  const float* sw3 = (const float*)d_in[7];
  const float* bias = (const float*)d_in[8];
  float* out = (float*)d_out;

  uint8_t* ws = (uint8_t*)d_ws;
  size_t off = 0;
  auto alloc = [&](size_t b) { size_t o = off; off += (b + 255) & ~(size_t)255; return o; };

  size_t ctrl = alloc(256);
  int* counts = (int*)(ws + ctrl);
  int* offsets = counts + 16;
  int* sel = (int*)(ws + alloc((size_t)NSLOT * 4));
  float* selscore = (float*)(ws + alloc((size_t)NSLOT * 4));
  float* slot_score = (float*)(ws + alloc((size_t)NPAD * 4));
  int* slot2pos = (int*)(ws + alloc((size_t)NSLOT * 4));
  u16* xb = (u16*)(ws + alloc((size_t)T_TOK * DIMSZ * 2));
  u16* routed = (u16*)(ws + alloc((size_t)NPAD * DIMSZ * 2));
  u16* Hbuf = (u16*)(ws + alloc((size_t)NPAD * HIDSZ * 2));
  u16* Orb = (u16*)(ws + alloc((size_t)NPAD * DIMSZ * 2));
  u16* Hs = (u16*)(ws + alloc((size_t)T_TOK * HIDSZ * 2));
  u16* w1b = (u16*)(ws + alloc((size_t)NE * HIDSZ * DIMSZ * 2));
  u16* w2b = (u16*)(ws + alloc((size_t)NE * DIMSZ * HIDSZ * 2));
  u16* w3b = (u16*)(ws + alloc((size_t)NE * HIDSZ * DIMSZ * 2));
  u16* sw1b = (u16*)(ws + alloc((size_t)HIDSZ * DIMSZ * 2));
  u16* sw2b = (u16*)(ws + alloc((size_t)DIMSZ * HIDSZ * 2));
  u16* sw3b = (u16*)(ws + alloc((size_t)HIDSZ * DIMSZ * 2));

  // weight conversion fp32 row-major -> bf16 blocked tiles
  convert_blocked<<<dim3(NE * 16 * 32, 3), 256, 0, stream>>>(
      w1, w2, w3, w1b, w2b, w3b);
  convert_blocked<<<dim3(16 * 32, 3), 256, 0, stream>>>(
      sw1, sw2, sw3, sw1b, sw2b, sw3b);

  router_kernel<<<T_TOK / 4, 256, 0, stream>>>(x, gw, bias, sel, selscore, xb);
  rank_kernel<<<1, 1024, 0, stream>>>(sel, selscore, slot2pos, slot_score,
                                      counts, offsets);
  gather_kernel<<<NSLOT / 4, 256, 0, stream>>>(x, selscore, slot2pos, routed);

  // unified GEMMs: z = 0..7 routed experts, z = 8 shared expert
  dual_glu_gemm<<<dim3(16, 64, NE + 1), 256, 0, stream>>>(
      routed, w1b, w3b, Hbuf, xb, sw1b, sw3b, Hs, offsets, counts);
  gemm2_kernel<<<dim3(8, 64, NE + 1), 256, 0, stream>>>(
      Hbuf, w2b, Orb, Hs, sw2b, out, slot_score, offsets, counts);

  // combine routed contributions into shared output
  combine_kernel<<<T_TOK, 256, 0, stream>>>(out, Orb, slot2pos);
}

// Round 9
// 495.559 us; speedup vs baseline: 1.3309x; 1.0588x over previous
//
#include <hip/hip_runtime.h>
#include <stdint.h>

typedef unsigned short u16;
typedef unsigned int u32;

#define T_TOK 8192      // B*S tokens
#define DIMSZ 1024
#define HIDSZ 1024
#define NE 8
#define NSLOT (T_TOK * 2)
#define NPAD (NSLOT + 1024)   // segment-aligned slot capacity

typedef __attribute__((ext_vector_type(8))) __bf16 bf16x8;
typedef __attribute__((ext_vector_type(16))) float f32x16;

#define MFMA32(a, b, c) __builtin_amdgcn_mfma_f32_32x32x16_bf16(a, b, c, 0, 0, 0)

// ---- blocked tile layouts (all GEMM operands, K = 1024, KT = 32) ----------
// A (activations, 128-row tiles):  [mt][kt][kc][row(128)][8]  (8 KB / tile)
// W (weights, 64-row tiles):       [nt][kt][kc][col(64)][8]   (4 KB / tile)
// Staging a tile = flat memcpy: global tile bytes == LDS tile bytes.
__device__ __forceinline__ size_t ablk(int pos, int c) {
  return ((((size_t)(pos >> 7) * 32 + (c >> 5)) * 4 + ((c >> 3) & 3)) * 128 +
          (pos & 127)) * 8 + (c & 7);
}

__device__ __forceinline__ u16 f2bf(float f) {
  u32 u = __builtin_bit_cast(u32, f);
  u += 0x7FFFu + ((u >> 16) & 1u);   // RNE
  return (u16)(u >> 16);
}
__device__ __forceinline__ float bflo(u32 v) { return __builtin_bit_cast(float, v << 16); }
__device__ __forceinline__ float bfhi(u32 v) { return __builtin_bit_cast(float, v & 0xffff0000u); }
__device__ __forceinline__ u32 pack2(float a, float b) {
  return (u32)f2bf(a) | ((u32)f2bf(b) << 16);
}
__device__ __forceinline__ float silu_f(float v) { return v / (1.f + expf(-v)); }

// ---------------- weight convert: fp32 row-major -> bf16 blocked (1 launch) --
__global__ __launch_bounds__(256) void convert_blocked(
    const float* __restrict__ s0, const float* __restrict__ s1,
    const float* __restrict__ s2, const float* __restrict__ ss0,
    const float* __restrict__ ss1, const float* __restrict__ ss2,
    u16* __restrict__ d0, u16* __restrict__ d1, u16* __restrict__ d2,
    u16* __restrict__ ds0, u16* __restrict__ ds1, u16* __restrict__ ds2) {
  __shared__ u16 lt[2048];
  int t = blockIdx.x;
  const float* s;
  u16* d;
  if (t < NE * 16 * 32) {
    s = (blockIdx.y == 0) ? s0 : (blockIdx.y == 1) ? s1 : s2;
    d = (blockIdx.y == 0) ? d0 : (blockIdx.y == 1) ? d1 : d2;
  } else {
    t -= NE * 16 * 32;
    s = (blockIdx.y == 0) ? ss0 : (blockIdx.y == 1) ? ss1 : ss2;
    d = (blockIdx.y == 0) ? ds0 : (blockIdx.y == 1) ? ds1 : ds2;
  }
  int rt = t >> 5, kt = t & 31;           // 64-row group, k-tile
  const float* sp = s + (size_t)rt * 64 * 1024 + kt * 32;
  int nl = threadIdx.x >> 2, k0 = (threadIdx.x & 3) * 8;
  float4 a = *(const float4*)(sp + (size_t)nl * 1024 + k0);
  float4 b = *(const float4*)(sp + (size_t)nl * 1024 + k0 + 4);
  uint4 p;
  p.x = pack2(a.x, a.y); p.y = pack2(a.z, a.w);
  p.z = pack2(b.x, b.y); p.w = pack2(b.z, b.w);
  *(uint4*)&lt[(threadIdx.x & 3) * 512 + nl * 8] = p;   // [kc][col][8]
  __syncthreads();
  *(uint4*)(d + (size_t)t * 2048 + threadIdx.x * 8) = *(const uint4*)&lt[threadIdx.x * 8];
}

// ---------------- router: fp32 scores, top-2; emits blocked bf16(x) ----------
__global__ __launch_bounds__(256) void router_kernel(
    const float* __restrict__ x, const float* __restrict__ gw,
    const float* __restrict__ bias, int* __restrict__ sel,
    float* __restrict__ selscore, u16* __restrict__ xb) {
  int t = blockIdx.x * 4 + (threadIdx.x >> 6);
  int lane = threadIdx.x & 63;
  float a[NE];
#pragma unroll
  for (int e = 0; e < NE; e++) a[e] = 0.f;
#pragma unroll
  for (int j = 0; j < 4; j++) {
    int c = j * 256 + lane * 4;
    float4 xv = *(const float4*)&x[(size_t)t * DIMSZ + c];
    uint2 p;
    p.x = pack2(xv.x, xv.y);
    p.y = pack2(xv.z, xv.w);
    *(uint2*)&xb[ablk(t, c)] = p;
#pragma unroll
    for (int e = 0; e < NE; e++) {
      float4 gv = *(const float4*)&gw[e * DIMSZ + c];
      a[e] = fmaf(xv.x, gv.x, fmaf(xv.y, gv.y, fmaf(xv.z, gv.z, fmaf(xv.w, gv.w, a[e]))));
    }
  }
#pragma unroll
  for (int off = 1; off < 64; off <<= 1)
#pragma unroll
    for (int e = 0; e < NE; e++) a[e] += __shfl_xor(a[e], off);
  if (lane == 0) {
    float s[NE], b[NE];
#pragma unroll
    for (int e = 0; e < NE; e++) {
      s[e] = 1.f / (1.f + expf(-a[e]));
      b[e] = s[e] + bias[e];
    }
    int e1 = 0; float v1 = b[0];
#pragma unroll
    for (int e = 1; e < NE; e++) if (b[e] > v1) { v1 = b[e]; e1 = e; }
    int e2 = -1; float v2 = -1e30f;
#pragma unroll
    for (int e = 0; e < NE; e++) if (e != e1 && b[e] > v2) { v2 = b[e]; e2 = e; }
    sel[t * 2] = e1; sel[t * 2 + 1] = e2;
    selscore[t * 2] = s[e1];       // ROUTE_SCALE == 1
    selscore[t * 2 + 1] = s[e2];
  }
}

// ---------------- rank: atomic-free permutation; 128-aligned segments --------
__global__ __launch_bounds__(1024) void rank_kernel(
    const int* __restrict__ sel, const float* __restrict__ selscore,
    int* __restrict__ slot2pos, float* __restrict__ slot_score,
    int* __restrict__ counts, int* __restrict__ offsets) {
  __shared__ int hist[NE * 1024];
  __shared__ int tot[NE];
  __shared__ int offs[NE];
  int tid = threadIdx.x;
  int sl[16];
  int h[NE];
#pragma unroll
  for (int e = 0; e < NE; e++) h[e] = 0;
#pragma unroll
  for (int j = 0; j < 4; j++) {
    int4 v = ((const int4*)sel)[tid * 4 + j];
    sl[j * 4 + 0] = v.x; sl[j * 4 + 1] = v.y;
    sl[j * 4 + 2] = v.z; sl[j * 4 + 3] = v.w;
  }
#pragma unroll
  for (int i = 0; i < 16; i++)
#pragma unroll
    for (int e = 0; e < NE; e++) h[e] += (sl[i] == e) ? 1 : 0;
#pragma unroll
  for (int e = 0; e < NE; e++) hist[e * 1024 + tid] = h[e];
  __syncthreads();
  int wid = tid >> 6, lane = tid & 63;
  if (wid < NE) {
    int e = wid;
    int vals[16];
    int lsum = 0;
#pragma unroll
    for (int i = 0; i < 16; i++) {
      int v = hist[e * 1024 + lane * 16 + i];
      vals[i] = lsum;
      lsum += v;
    }
    int incl = lsum;
#pragma unroll
    for (int off = 1; off < 64; off <<= 1) {
      int v = __shfl_up(incl, off);
      if (lane >= off) incl += v;
    }
    int excl = incl - lsum;
#pragma unroll
    for (int i = 0; i < 16; i++) hist[e * 1024 + lane * 16 + i] = vals[i] + excl;
    if (lane == 63) tot[e] = incl;
  }
  __syncthreads();
  if (tid == 0) {
    int acc = 0;
    for (int e = 0; e < NE; e++) {
      offs[e] = acc;
      offsets[e] = acc;
      counts[e] = tot[e];
      acc += (tot[e] + 127) & ~127;   // 128-align every segment
    }
  }
  __syncthreads();
  int base[NE];
#pragma unroll
  for (int e = 0; e < NE; e++) base[e] = offs[e] + hist[e * 1024 + tid];
#pragma unroll
  for (int i = 0; i < 16; i++) {
    int slot = tid * 16 + i;
    int e = sl[i];
    int pos = 0;
#pragma unroll
    for (int k = 0; k < NE; k++) pos += (e == k) ? base[k] : 0;
#pragma unroll
    for (int k = 0; k < NE; k++) base[k] += (e == k) ? 1 : 0;
    slot2pos[slot] = pos;
    slot_score[pos] = selscore[slot];
  }
}

// ---------------- gather: slot -> blocked row pos of bf16(s*x) ---------------
__global__ __launch_bounds__(256) void gather_kernel(
    const float* __restrict__ x, const float* __restrict__ selscore,
    const int* __restrict__ slot2pos, u16* __restrict__ routed) {
  int s = blockIdx.x * 4 + (threadIdx.x >> 6);
  int lane = threadIdx.x & 63;
  int pos = slot2pos[s];
  float sc = selscore[s];
  int t = s >> 1;
#pragma unroll
  for (int j = 0; j < 4; j++) {
    int c = j * 256 + lane * 4;
    float4 v = *(const float4*)&x[(size_t)t * DIMSZ + c];
    uint2 p;
    p.x = pack2(v.x * sc, v.y * sc);
    p.y = pack2(v.z * sc, v.w * sc);
    *(uint2*)&routed[ablk(pos, c)] = p;
  }
}

// ---------------- dual GEMM (G1,G3 share A-tile) + silu*mul -> H (blocked) ---
// BM=128 BN=64 BK=32, mfma 32x32x16. Static dbuf, unroll-2 K loop:
//   store kt->buf0; sync; load kt+1; compute buf0; store kt+1->buf1; sync; ...
// Safety: writer of bufX and prior reader of bufX separated by one barrier.
__global__ __launch_bounds__(256, 3) void dual_glu_gemm(
    const u16* __restrict__ A, const u16* __restrict__ W1,
    const u16* __restrict__ W3, u16* __restrict__ Hout,
    const u16* __restrict__ As, const u16* __restrict__ SW1,
    const u16* __restrict__ SW3, u16* __restrict__ Hs,
    const int* __restrict__ seg_off, const int* __restrict__ seg_cnt) {
  int z = blockIdx.z;
  const u16 *Ap, *w1p, *w3p;
  u16* Hp;
  int soff, scnt;
  if (z < NE) {
    soff = seg_off[z]; scnt = seg_cnt[z];
    Ap = A;
    w1p = W1 + (size_t)z * HIDSZ * DIMSZ;
    w3p = W3 + (size_t)z * HIDSZ * DIMSZ;
    Hp = Hout;
  } else {
    soff = 0; scnt = T_TOK;
    Ap = As; w1p = SW1; w3p = SW3;
    Hp = Hs;
  }
  int mbase = blockIdx.y * 128;
  if (mbase >= scnt) return;
  int nbase = blockIdx.x * 64;

  __shared__ u16 lA[2][4096];   // [kc4][row128][8]
  __shared__ u16 lB1[2][2048];  // [kc4][col64][8]
  __shared__ u16 lB3[2][2048];

  int tid = threadIdx.x;
  int lane = tid & 63;
  int wid = tid >> 6;
  int wy = wid >> 1, wx = wid & 1;
  int l5 = lane >> 5, l31 = lane & 31;
  int aoff = (l5 * 128 + wy * 64 + l31) * 8;   // + s*2048 + i*256
  int boff = (l5 * 64 + wx * 32 + l31) * 8;    // + s*1024

  f32x16 acc1[2], acc3[2];
  acc1[0] = (f32x16)0.f; acc1[1] = (f32x16)0.f;
  acc3[0] = (f32x16)0.f; acc3[1] = (f32x16)0.f;

  const u16* gA = Ap + ((size_t)((soff + mbase) >> 7) * 32) * 4096 + tid * 8;
  const u16* gB1 = w1p + ((size_t)(nbase >> 6) * 32) * 2048 + tid * 8;
  const u16* gB3 = w3p + ((size_t)(nbase >> 6) * 32) * 2048 + tid * 8;

  uint4 rA0 = *(const uint4*)gA;
  uint4 rA1 = *(const uint4*)(gA + 2048);
  uint4 rB1 = *(const uint4*)gB1;
  uint4 rB3 = *(const uint4*)gB3;
  gA += 4096; gB1 += 2048; gB3 += 2048;

#define DG_STAGE(B)                                                   \
  *(uint4*)&lA[B][tid * 8] = rA0;                                     \
  *(uint4*)&lA[B][2048 + tid * 8] = rA1;                              \
  *(uint4*)&lB1[B][tid * 8] = rB1;                                    \
  *(uint4*)&lB3[B][tid * 8] = rB3;

#define DG_LOAD()                                                     \
  rA0 = *(const uint4*)gA;                                            \
  rA1 = *(const uint4*)(gA + 2048);                                   \
  rB1 = *(const uint4*)gB1;                                           \
  rB3 = *(const uint4*)gB3;                                           \
  gA += 4096; gB1 += 2048; gB3 += 2048;

#define DG_COMPUTE(B)                                                 \
  _Pragma("unroll")                                                   \
  for (int s = 0; s < 2; s++) {                                       \
    bf16x8 a0 = *(const bf16x8*)&lA[B][aoff + s * 2048];              \
    bf16x8 a1 = *(const bf16x8*)&lA[B][aoff + s * 2048 + 256];        \
    bf16x8 b1 = *(const bf16x8*)&lB1[B][boff + s * 1024];             \
    bf16x8 b3 = *(const bf16x8*)&lB3[B][boff + s * 1024];             \
    acc1[0] = MFMA32(a0, b1, acc1[0]);                                \
    acc3[0] = MFMA32(a0, b3, acc3[0]);                                \
    acc1[1] = MFMA32(a1, b1, acc1[1]);                                \
    acc3[1] = MFMA32(a1, b3, acc3[1]);                                \
  }

  for (int kt = 0; kt < 32; kt += 2) {
    DG_STAGE(0);
    __syncthreads();
    DG_LOAD();          // tile kt+1 (always exists: kt <= 30)
    DG_COMPUTE(0);
    DG_STAGE(1);
    __syncthreads();
    if (kt < 30) { DG_LOAD(); }   // tile kt+2
    DG_COMPUTE(1);
  }

#pragma unroll
  for (int i = 0; i < 2; i++) {
    int colg = nbase + wx * 32 + l31;
#pragma unroll
    for (int r = 0; r < 16; r++) {
      int rowl = (r & 3) + 8 * (r >> 2) + 4 * l5;
      int grow = mbase + wy * 64 + i * 32 + rowl;
      if (grow < scnt)
        Hp[ablk(soff + grow, colg)] = f2bf(silu_f(acc1[i][r]) * acc3[i][r]);
    }
  }
}

// ---------------- GEMM2: Out = (A @ W^T) * scale, BM=128 BN=128 BK=32 --------
__global__ __launch_bounds__(256, 3) void gemm2_kernel(
    const u16* __restrict__ A, const u16* __restrict__ W, u16* __restrict__ OutB,
    const u16* __restrict__ As, const u16* __restrict__ SW, float* __restrict__ OutF,
    const float* __restrict__ scale, const int* __restrict__ seg_off,
    const int* __restrict__ seg_cnt) {
  int z = blockIdx.z;
  const u16 *Ap, *wp;
  int soff, scnt;
  if (z < NE) {
    soff = seg_off[z]; scnt = seg_cnt[z];
    Ap = A; wp = W + (size_t)z * DIMSZ * HIDSZ;
  } else {
    soff = 0; scnt = T_TOK;
    Ap = As; wp = SW;
  }
  int mbase = blockIdx.y * 128;
  if (mbase >= scnt) return;
  int nbase = blockIdx.x * 128;

  __shared__ u16 lA[2][4096];   // [kc4][row128][8]
  __shared__ u16 lB[2][4096];   // [half][kc4][col64][8]

  int tid = threadIdx.x;
  int lane = tid & 63;
  int wid = tid >> 6;
  int wy = wid >> 1, wx = wid & 1;
  int l5 = lane >> 5, l31 = lane & 31;
  int aoff = (l5 * 128 + wy * 64 + l31) * 8;        // + s*2048 + i*256
  int boff = wx * 2048 + (l5 * 64 + l31) * 8;       // + s*1024 + j*256

  f32x16 acc[2][2];
  acc[0][0] = (f32x16)0.f; acc[0][1] = (f32x16)0.f;
  acc[1][0] = (f32x16)0.f; acc[1][1] = (f32x16)0.f;

  const u16* gA = Ap + ((size_t)((soff + mbase) >> 7) * 32) * 4096 + tid * 8;
  const u16* gB0 = wp + ((size_t)(nbase >> 6) * 32) * 2048 + tid * 8;
  const u16* gB1 = wp + ((size_t)((nbase >> 6) + 1) * 32) * 2048 + tid * 8;

  uint4 rA0 = *(const uint4*)gA;
  uint4 rA1 = *(const uint4*)(gA + 2048);
  uint4 rB0 = *(const uint4*)gB0;
  uint4 rB1 = *(const uint4*)gB1;
  gA += 4096; gB0 += 2048; gB1 += 2048;

#define G2_STAGE(B)                                                   \
  *(uint4*)&lA[B][tid * 8] = rA0;                                     \
  *(uint4*)&lA[B][2048 + tid * 8] = rA1;                              \
  *(uint4*)&lB[B][tid * 8] = rB0;                                     \
  *(uint4*)&lB[B][2048 + tid * 8] = rB1;

#define G2_LOAD()                                                     \
  rA0 = *(const uint4*)gA;                                            \
  rA1 = *(const uint4*)(gA + 2048);                                   \
  rB0 = *(const uint4*)gB0;                                           \
  rB1 = *(const uint4*)gB1;                                           \
  gA += 4096; gB0 += 2048; gB1 += 2048;

#define G2_COMPUTE(B)                                                 \
  _Pragma("unroll")                                                   \
  for (int s = 0; s < 2; s++) {                                       \
    bf16x8 a0 = *(const bf16x8*)&lA[B][aoff + s * 2048];              \
    bf16x8 a1 = *(const bf16x8*)&lA[B][aoff + s * 2048 + 256];        \
    bf16x8 b0 = *(const bf16x8*)&lB[B][boff + s * 1024];              \
    bf16x8 b1 = *(const bf16x8*)&lB[B][boff + s * 1024 + 256];        \
    acc[0][0] = MFMA32(a0, b0, acc[0][0]);                            \
    acc[0][1] = MFMA32(a0, b1, acc[0][1]);                            \
    acc[1][0] = MFMA32(a1, b0, acc[1][0]);                            \
    acc[1][1] = MFMA32(a1, b1, acc[1][1]);                            \
  }

  for (int kt = 0; kt < 32; kt += 2) {
    G2_STAGE(0);
    __syncthreads();
    G2_LOAD();
    G2_COMPUTE(0);
    G2_STAGE(1);
    __syncthreads();
    if (kt < 30) { G2_LOAD(); }
    G2_COMPUTE(1);
  }

#pragma unroll
  for (int i = 0; i < 2; i++) {
#pragma unroll
    for (int j = 0; j < 2; j++) {
      int colg = nbase + wx * 64 + j * 32 + l31;
#pragma unroll
      for (int r = 0; r < 16; r++) {
        int rowl = (r & 3) + 8 * (r >> 2) + 4 * l5;
        int grow = mbase + wy * 64 + i * 32 + rowl;
        if (grow < scnt) {
          size_t idx = (size_t)(soff + grow) * DIMSZ + colg;
          if (z < NE) {
            OutB[idx] = f2bf(acc[i][j][r] * scale[soff + grow]);
          } else {
            OutF[idx] = acc[i][j][r];
          }
        }
      }
    }
  }
}

// ---------------- combine: out[t] += Or[pos(t,0)] + Or[pos(t,1)] -------------
__global__ __launch_bounds__(256) void combine_kernel(
    float* __restrict__ out, const u16* __restrict__ Orb,
    const int* __restrict__ slot2pos) {
  int t = blockIdx.x;
  int d = threadIdx.x * 4;
  int p0 = slot2pos[t * 2];
  int p1 = slot2pos[t * 2 + 1];
  float4 o = *(float4*)&out[(size_t)t * DIMSZ + d];
  uint2 a = *(const uint2*)&Orb[(size_t)p0 * DIMSZ + d];
  uint2 b = *(const uint2*)&Orb[(size_t)p1 * DIMSZ + d];
  o.x += bflo(a.x) + bflo(b.x);
  o.y += bfhi(a.x) + bfhi(b.x);
  o.z += bflo(a.y) + bflo(b.y);
  o.w += bfhi(a.y) + bfhi(b.y);
  *(float4*)&out[(size_t)t * DIMSZ + d] = o;
}

extern "C" void kernel_launch(void* const* d_in, const int* in_sizes, int n_in,
                              void* d_out, int out_size, void* d_ws, size_t ws_size,
                              hipStream_t stream) {
  const float* x = (const float*)d_in[0];
  const float* gw = (const float*)d_in[1];
  const float* w1 = (const float*)d_in[2];
  const float* w2 = (const float*)d_in[3];
  const float* w3 = (const float*)d_in[4];
  const float* sw1 = (const float*)d_in[5];
  const float* sw2 = (const float*)d_in[6];
  const float* sw3 = (const float*)d_in[7];
  const float* bias = (const float*)d_in[8];
  float* out = (float*)d_out;

  uint8_t* ws = (uint8_t*)d_ws;
  size_t off = 0;
  auto alloc = [&](size_t b) { size_t o = off; off += (b + 255) & ~(size_t)255; return o; };

  size_t ctrl = alloc(256);
  int* counts = (int*)(ws + ctrl);
  int* offsets = counts + 16;
  int* sel = (int*)(ws + alloc((size_t)NSLOT * 4));
  float* selscore = (float*)(ws + alloc((size_t)NSLOT * 4));
  float* slot_score = (float*)(ws + alloc((size_t)NPAD * 4));
  int* slot2pos = (int*)(ws + alloc((size_t)NSLOT * 4));
  u16* xb = (u16*)(ws + alloc((size_t)T_TOK * DIMSZ * 2));
  u16* routed = (u16*)(ws + alloc((size_t)NPAD * DIMSZ * 2));
  u16* Hbuf = (u16*)(ws + alloc((size_t)NPAD * HIDSZ * 2));
  u16* Orb = (u16*)(ws + alloc((size_t)NPAD * DIMSZ * 2));
  u16* Hs = (u16*)(ws + alloc((size_t)T_TOK * HIDSZ * 2));
  u16* w1b = (u16*)(ws + alloc((size_t)NE * HIDSZ * DIMSZ * 2));
  u16* w2b = (u16*)(ws + alloc((size_t)NE * DIMSZ * HIDSZ * 2));
  u16* w3b = (u16*)(ws + alloc((size_t)NE * HIDSZ * DIMSZ * 2));
  u16* sw1b = (u16*)(ws + alloc((size_t)HIDSZ * DIMSZ * 2));
  u16* sw2b = (u16*)(ws + alloc((size_t)DIMSZ * HIDSZ * 2));
  u16* sw3b = (u16*)(ws + alloc((size_t)HIDSZ * DIMSZ * 2));

  // weight conversion fp32 row-major -> bf16 blocked tiles (single launch)
  convert_blocked<<<dim3((NE + 1) * 16 * 32, 3), 256, 0, stream>>>(
      w1, w2, w3, sw1, sw2, sw3, w1b, w2b, w3b, sw1b, sw2b, sw3b);

  router_kernel<<<T_TOK / 4, 256, 0, stream>>>(x, gw, bias, sel, selscore, xb);
  rank_kernel<<<1, 1024, 0, stream>>>(sel, selscore, slot2pos, slot_score,
                                      counts, offsets);
  gather_kernel<<<NSLOT / 4, 256, 0, stream>>>(x, selscore, slot2pos, routed);

  // unified GEMMs: z = 0..7 routed experts, z = 8 shared expert
  dual_glu_gemm<<<dim3(16, 64, NE + 1), 256, 0, stream>>>(
      routed, w1b, w3b, Hbuf, xb, sw1b, sw3b, Hs, offsets, counts);
  gemm2_kernel<<<dim3(8, 64, NE + 1), 256, 0, stream>>>(
      Hbuf, w2b, Orb, Hs, sw2b, out, slot_score, offsets, counts);

  // combine routed contributions into shared output
  combine_kernel<<<T_TOK, 256, 0, stream>>>(out, Orb, slot2pos);
}